// Round 1
// baseline (297.071 us; speedup 1.0000x reference)
//
#include <hip/hip_runtime.h>

// Problem constants
#define HW 4096      // 64*64 pixels per image
#define NC 256       // C_in
#define ND 256       // C_out
// derived: RK = 256 (r*16+k), EG = 256 (e*16+g)

// ---------------------------------------------------------------------------
// prep: W1[c*256 + r*16 + k] = w_core[r*4096 + c*16 + k]   (GEMM1 B-operand)
//       W2[(e*16+g)*256 + d] = w_out [g*4096 + d*16 + e]   (GEMM2 B-operand)
// ---------------------------------------------------------------------------
__global__ __launch_bounds__(256) void prep_weights(
        const float* __restrict__ w_core, const float* __restrict__ w_out,
        float* __restrict__ W1, float* __restrict__ W2) {
    int t = blockIdx.x * 256 + threadIdx.x;      // grid = 512 blocks -> 131072
    if (t < 65536) {
        int c = t >> 8, r = (t >> 4) & 15, k = t & 15;
        W1[t] = w_core[r * 4096 + c * 16 + k];
    } else {
        int o = t - 65536;
        int e = o >> 12, g = (o >> 8) & 15, d = o & 255;
        W2[o] = w_out[g * 4096 + d * 16 + e];
    }
}

// ---------------------------------------------------------------------------
// Fused per-32-pixel-tile: M = x^T W1  ->  P = M*M  ->  y = P_flat * W2
// block = 256 threads (4 waves), grid = 16*128 = 2048 (one tile = 32 pixels of
// one image row). LDS: two 32KB regions -> 64KB total -> 2 blocks/CU.
// ---------------------------------------------------------------------------
__global__ __launch_bounds__(256, 2) void compute_y(
        const float* __restrict__ x, const float* __restrict__ W1,
        const float* __restrict__ W2, float* __restrict__ y) {
    __shared__ float sA[8192];   // W1 chunk [32][256]  ->  P [256 eg][32 pix]
    __shared__ float sB[8192];   // M [32 pix][256 rk] (xor-swizzled) -> W2 chunk

    const int t  = threadIdx.x;
    const int pg = t & 7;                 // pixel group (4 pixels)
    const int rg = t >> 3;                // rk / d group (8 outputs)   0..31
    const int a  = blockIdx.x >> 7;
    const int p0 = (blockIdx.x & 127) * 32;

    const float* xa = x + (size_t)a * NC * HW + p0 + 4 * pg;

    // ---------------- stage A: M[pix][rk] = sum_c x[c][pix] * W1[c][rk] -----
    float acc[4][8];
#pragma unroll
    for (int i = 0; i < 4; ++i)
#pragma unroll
        for (int j = 0; j < 8; ++j) acc[i][j] = 0.f;

    for (int cc = 0; cc < 8; ++cc) {
        __syncthreads();
#pragma unroll
        for (int q = 0; q < 8; ++q)
            ((float4*)sA)[t + q * 256] =
                ((const float4*)(W1 + cc * 8192))[t + q * 256];
        __syncthreads();
#pragma unroll 8
        for (int cl = 0; cl < 32; ++cl) {
            const int c = cc * 32 + cl;
            float4 xv = *(const float4*)(xa + (size_t)c * HW);   // L1-hot
            float4 wa = *(const float4*)&sA[cl * 256 + 8 * rg];
            float4 wb = *(const float4*)&sA[cl * 256 + 8 * rg + 4];
            float xs[4]  = {xv.x, xv.y, xv.z, xv.w};
            float wsv[8] = {wa.x, wa.y, wa.z, wa.w, wb.x, wb.y, wb.z, wb.w};
#pragma unroll
            for (int i = 0; i < 4; ++i)
#pragma unroll
                for (int j = 0; j < 8; ++j)
                    acc[i][j] = fmaf(xs[i], wsv[j], acc[i][j]);
        }
    }

    // write M -> sB, rk index xor-swizzled per pixel (avoids stride-16 bank
    // conflicts in stage B column reads; swizzle flips word-bits 2..4 only,
    // so float4 alignment is preserved)
#pragma unroll
    for (int i = 0; i < 4; ++i) {
        const int pix = 4 * pg + i;
        const int sw  = (pix & 7) << 2;
        *(float4*)&sB[pix * 256 + ((8 * rg) ^ sw)] =
            make_float4(acc[i][0], acc[i][1], acc[i][2], acc[i][3]);
        *(float4*)&sB[pix * 256 + ((8 * rg + 4) ^ sw)] =
            make_float4(acc[i][4], acc[i][5], acc[i][6], acc[i][7]);
    }
    __syncthreads();

    // ---------------- stage B: P[e][g] = sum_f M[e][f] * M[f][g] ------------
    {
        const int pix = t >> 3;           // 0..31
        const int sub = t & 7;            // owns e rows 2*sub, 2*sub+1
        const int sw  = (pix & 7) << 2;
        const float* Mp = &sB[pix * 256];
        float rowA[16], rowB[16], pa0[16], pa1[16];
#pragma unroll
        for (int q = 0; q < 4; ++q) {
            float4 va = *(const float4*)&Mp[(32 * sub + 4 * q) ^ sw];
            float4 vb = *(const float4*)&Mp[(32 * sub + 16 + 4 * q) ^ sw];
            rowA[4*q] = va.x; rowA[4*q+1] = va.y; rowA[4*q+2] = va.z; rowA[4*q+3] = va.w;
            rowB[4*q] = vb.x; rowB[4*q+1] = vb.y; rowB[4*q+2] = vb.z; rowB[4*q+3] = vb.w;
        }
#pragma unroll
        for (int g = 0; g < 16; ++g) { pa0[g] = 0.f; pa1[g] = 0.f; }
#pragma unroll
        for (int f = 0; f < 16; ++f) {
#pragma unroll
            for (int gq = 0; gq < 4; ++gq) {
                float4 mv = *(const float4*)&Mp[(16 * f + 4 * gq) ^ sw];
                float mvv[4] = {mv.x, mv.y, mv.z, mv.w};
#pragma unroll
                for (int l = 0; l < 4; ++l) {
                    pa0[4*gq+l] = fmaf(rowA[f], mvv[l], pa0[4*gq+l]);
                    pa1[4*gq+l] = fmaf(rowB[f], mvv[l], pa1[4*gq+l]);
                }
            }
        }
        // P -> sA as [eg][pix]  (eg = e*16+g; e = 2*sub -> eg = 32*sub + g)
#pragma unroll
        for (int g = 0; g < 16; ++g) {
            sA[(32 * sub + g) * 32 + pix]      = pa0[g];
            sA[(32 * sub + 16 + g) * 32 + pix] = pa1[g];
        }
    }
    __syncthreads();

    // ---------------- stage C: y[pix][d] = sum_eg P[eg][pix] * W2[eg][d] ----
    const int dg = rg;
    float yacc[4][8];
#pragma unroll
    for (int i = 0; i < 4; ++i)
#pragma unroll
        for (int j = 0; j < 8; ++j) yacc[i][j] = 0.f;

    for (int ec = 0; ec < 8; ++ec) {
        __syncthreads();
#pragma unroll
        for (int q = 0; q < 8; ++q)
            ((float4*)sB)[t + q * 256] =
                ((const float4*)(W2 + ec * 8192))[t + q * 256];
        __syncthreads();
#pragma unroll 8
        for (int el = 0; el < 32; ++el) {
            float4 pv = *(const float4*)&sA[(ec * 32 + el) * 32 + 4 * pg];
            float4 wa = *(const float4*)&sB[el * 256 + 8 * dg];
            float4 wb = *(const float4*)&sB[el * 256 + 8 * dg + 4];
            float ps[4]  = {pv.x, pv.y, pv.z, pv.w};
            float wsv[8] = {wa.x, wa.y, wa.z, wa.w, wb.x, wb.y, wb.z, wb.w};
#pragma unroll
            for (int i = 0; i < 4; ++i)
#pragma unroll
                for (int j = 0; j < 8; ++j)
                    yacc[i][j] = fmaf(ps[i], wsv[j], yacc[i][j]);
        }
    }

    float* ya = y + (size_t)a * ND * HW + p0 + 4 * pg;
#pragma unroll
    for (int j = 0; j < 8; ++j) {
        const int d = 8 * dg + j;
        *(float4*)(ya + (size_t)d * HW) =
            make_float4(yacc[0][j], yacc[1][j], yacc[2][j], yacc[3][j]);
    }
}

// ---------------------------------------------------------------------------
// stats: one block per (a,d); mean + biased var over the contiguous 4096 row
// ---------------------------------------------------------------------------
__global__ __launch_bounds__(256) void stats_kernel(
        const float* __restrict__ y, float* __restrict__ mean_o,
        float* __restrict__ istd_o) {
    const int ad = blockIdx.x;
    const float* row = y + (size_t)ad * HW;
    const int t = threadIdx.x;
    float s = 0.f, ss = 0.f;
#pragma unroll
    for (int q = 0; q < 4; ++q) {
        float4 v = *(const float4*)&row[4 * (t + q * 256)];
        s  += v.x + v.y + v.z + v.w;
        ss += v.x * v.x + v.y * v.y + v.z * v.z + v.w * v.w;
    }
#pragma unroll
    for (int off = 32; off > 0; off >>= 1) {
        s  += __shfl_down(s, off);
        ss += __shfl_down(ss, off);
    }
    __shared__ float ps[4], pq[4];
    if ((t & 63) == 0) { ps[t >> 6] = s; pq[t >> 6] = ss; }
    __syncthreads();
    if (t == 0) {
        s  = ps[0] + ps[1] + ps[2] + ps[3];
        ss = pq[0] + pq[1] + pq[2] + pq[3];
        float mean = s * (1.f / HW);
        float var  = ss * (1.f / HW) - mean * mean;
        mean_o[ad] = mean;
        istd_o[ad] = rsqrtf(var + 1e-5f);
    }
}

// ---------------------------------------------------------------------------
// finalize: in-place (y - mean) * istd -> softsign
// ---------------------------------------------------------------------------
__global__ __launch_bounds__(256) void finalize_kernel(
        float* __restrict__ y, const float* __restrict__ mean_a,
        const float* __restrict__ istd_a) {
    const int i4 = blockIdx.x * 256 + threadIdx.x;   // float4 index
    const int ad = i4 >> 10;                          // 1024 float4 per (a,d)
    const float m = mean_a[ad], s = istd_a[ad];
    float4 v = ((const float4*)y)[i4];
    float vv[4] = {v.x, v.y, v.z, v.w};
#pragma unroll
    for (int l = 0; l < 4; ++l) {
        float z = (vv[l] - m) * s;
        vv[l] = z / (1.f + fabsf(z));
    }
    ((float4*)y)[i4] = make_float4(vv[0], vv[1], vv[2], vv[3]);
}

// ---------------------------------------------------------------------------
extern "C" void kernel_launch(void* const* d_in, const int* in_sizes, int n_in,
                              void* d_out, int out_size, void* d_ws, size_t ws_size,
                              hipStream_t stream) {
    const float* x      = (const float*)d_in[0];
    const float* w_core = (const float*)d_in[1];
    const float* w_out  = (const float*)d_in[2];
    float* y  = (float*)d_out;        // y computed in-place in d_out
    float* ws = (float*)d_ws;
    float* W1     = ws;               // 65536 floats
    float* W2     = ws + 65536;       // 65536 floats
    float* mean_a = ws + 131072;      // 4096
    float* istd_a = ws + 135168;      // 4096  (total ws use: 544 KB)

    prep_weights<<<512, 256, 0, stream>>>(w_core, w_out, W1, W2);
    compute_y<<<2048, 256, 0, stream>>>(x, W1, W2, y);
    stats_kernel<<<4096, 256, 0, stream>>>(y, mean_a, istd_a);
    finalize_kernel<<<16384, 256, 0, stream>>>(y, mean_a, istd_a);
}

// Round 2
// 94.387 us; speedup vs baseline: 3.1474x; 3.1474x over previous
//
#include <hip/hip_runtime.h>

#define HW 4096      // 64*64 pixels per image
#define NC 256       // C_in
#define ND 256       // C_out

typedef _Float16 half4_t __attribute__((ext_vector_type(4)));
typedef _Float16 half8_t __attribute__((ext_vector_type(8)));
typedef float floatx4 __attribute__((ext_vector_type(4)));

#define MSCALE 64.0f                 // M scaled by 2^6 -> P by 2^12 (keeps f16 normal)
#define INV_MSCALE2 (1.0f / 4096.0f)

// ---------------------------------------------------------------------------
// prep: pack A-operand fragment streams for mfma_f32_16x16x32_f16.
// Fragment layout assumed: lane l -> row = l&15, k = (l>>4)*8 + j (j=0..7
// contiguous). Stream address: ((tile*8 + kstep)*64 + l)*8 + j.
// W1T[rk][c] = w_core[r][c][k] * 64 ;  W2T[d][eg] = w_out[g][d][e]
// ---------------------------------------------------------------------------
__global__ __launch_bounds__(256) void prep_weights(
        const float* __restrict__ w_core, const float* __restrict__ w_out,
        _Float16* __restrict__ W1p, _Float16* __restrict__ W2p) {
    int tid = blockIdx.x * 256 + threadIdx.x;   // 16384 threads
    int l   = tid & 63;
    int ks  = (tid >> 6) & 7;
    int rt  = (tid >> 9) & 15;
    int sel = tid >> 13;
    int row = l & 15, kg = l >> 4;
    half8_t v;
    if (sel == 0) {
        int rk = rt * 16 + row, r = rk >> 4, k = rk & 15;
#pragma unroll
        for (int j = 0; j < 8; ++j) {
            int c = ks * 32 + kg * 8 + j;
            v[j] = (_Float16)(w_core[r * 4096 + c * 16 + k] * MSCALE);
        }
        *(half8_t*)&W1p[(size_t)((rt * 8 + ks) * 64 + l) * 8] = v;
    } else {
        int d = rt * 16 + row;
#pragma unroll
        for (int j = 0; j < 8; ++j) {
            int eg = ks * 32 + kg * 8 + j, e = eg >> 4, g = eg & 15;
            v[j] = (_Float16)w_out[g * 4096 + d * 16 + e];
        }
        *(half8_t*)&W2p[(size_t)((rt * 8 + ks) * 64 + l) * 8] = v;
    }
}

// ---------------------------------------------------------------------------
// Fused MFMA kernel: 64 pixels per block, 4 waves.
//  A: MT[rk][pix] = W1T . x          (MFMA, acc f32, stored f16 to LDS)
//  B: P[pix] = M_pix * M_pix         (VALU f32, 4 threads/pixel, f16 to LDS)
//  C: yT[d][pix] = W2T . P  * 2^-12  (MFMA, f32 stores; layout == memory)
// LDS: MT 32KB + PL 32KB -> 2 blocks/CU.
// ---------------------------------------------------------------------------
__global__ __launch_bounds__(256, 2) void compute_y(
        const float* __restrict__ x, const _Float16* __restrict__ W1p,
        const _Float16* __restrict__ W2p, float* __restrict__ y) {
    __shared__ ushort MT[64 * 256];  // [pix][rk]  f16, rk swizzled in 4-elem units
    __shared__ ushort PL[64 * 256];  // [pix][eg]  f16, eg swizzled in 8-elem units

    const int t   = threadIdx.x;
    const int l   = t & 63;          // lane
    const int w   = t >> 6;          // wave 0..3
    const int a   = blockIdx.x >> 6;
    const int pixbase = (blockIdx.x & 63) * 64;   // image-local pixel base
    const int row16 = l & 15;
    const int kg    = l >> 4;

    const int lpix = w * 16 + row16;              // block-local pixel (stages A,C)
    const int wpix = pixbase + lpix;              // image-local pixel
    const float* xa = x + (size_t)a * NC * HW;

    // ---- B-fragments from x (x[c][pix] is exactly B layout: col=pix, k=c) ----
    half8_t bx[8];
#pragma unroll
    for (int ks = 0; ks < 8; ++ks) {
#pragma unroll
        for (int j = 0; j < 8; ++j) {
            int c = ks * 32 + kg * 8 + j;
            bx[ks][j] = (_Float16)xa[(size_t)c * HW + wpix];
        }
    }

    // ---- stage A: 16 rk-tiles x 8 ksteps of MFMA ----
    const half8_t* W1v = (const half8_t*)W1p;
    const int psw = lpix & 7;
#pragma unroll
    for (int rtg = 0; rtg < 4; ++rtg) {
        floatx4 acc[4] = {{0.f,0.f,0.f,0.f},{0.f,0.f,0.f,0.f},
                          {0.f,0.f,0.f,0.f},{0.f,0.f,0.f,0.f}};
#pragma unroll
        for (int ks = 0; ks < 8; ++ks) {
#pragma unroll
            for (int i = 0; i < 4; ++i) {
                int rt = rtg * 4 + i;
                acc[i] = __builtin_amdgcn_mfma_f32_16x16x32_f16(
                             W1v[(rt * 8 + ks) * 64 + l], bx[ks], acc[i], 0, 0, 0);
            }
        }
        // D layout: col=pix=l&15, row=rk = rt*16 + kg*4 + reg  -> MT[lpix][rk]
#pragma unroll
        for (int i = 0; i < 4; ++i) {
            int rt  = rtg * 4 + i;
            int rk4 = rt * 4 + kg;               // rk0/4
            half4_t hv;
#pragma unroll
            for (int r2 = 0; r2 < 4; ++r2) hv[r2] = (_Float16)acc[i][r2];
            *(half4_t*)&MT[lpix * 256 + ((rk4 ^ psw) << 2)] = hv;
        }
    }
    __syncthreads();

    // ---- stage B: per-pixel P = M*M (4 threads per pixel) ----
    {
        const int p   = t >> 2;      // block-local pixel 0..63
        const int q   = t & 3;       // e-quarter
        const int pswb = p & 7;
        float Af[4][16];
#pragma unroll
        for (int i = 0; i < 4; ++i) {
            int e = q * 4 + i;
#pragma unroll
            for (int f4 = 0; f4 < 4; ++f4) {
                half4_t v = *(const half4_t*)&MT[p * 256 + (((e * 4 + f4) ^ pswb) << 2)];
#pragma unroll
                for (int j = 0; j < 4; ++j) Af[i][f4 * 4 + j] = (float)v[j];
            }
        }
        float Pacc[4][16];
#pragma unroll
        for (int i = 0; i < 4; ++i)
#pragma unroll
            for (int g = 0; g < 16; ++g) Pacc[i][g] = 0.f;
#pragma unroll
        for (int f = 0; f < 16; ++f) {
            float Bg[16];
#pragma unroll
            for (int g4 = 0; g4 < 4; ++g4) {
                half4_t v = *(const half4_t*)&MT[p * 256 + (((f * 4 + g4) ^ pswb) << 2)];
#pragma unroll
                for (int j = 0; j < 4; ++j) Bg[g4 * 4 + j] = (float)v[j];
            }
#pragma unroll
            for (int i = 0; i < 4; ++i)
#pragma unroll
                for (int g = 0; g < 16; ++g)
                    Pacc[i][g] = fmaf(Af[i][f], Bg[g], Pacc[i][g]);
        }
        // write P[pix][eg] f16 (eg swizzled in 8-elem units)
#pragma unroll
        for (int i = 0; i < 4; ++i) {
            int e = q * 4 + i;
#pragma unroll
            for (int h = 0; h < 2; ++h) {
                half8_t hv;
#pragma unroll
                for (int j = 0; j < 8; ++j) hv[j] = (_Float16)Pacc[i][h * 8 + j];
                *(half8_t*)&PL[p * 256 + (((e * 2 + h) ^ pswb) << 3)] = hv;
            }
        }
    }
    __syncthreads();

    // ---- stage C: yT[d][pix] = W2T . P ----
    half8_t pb[8];
#pragma unroll
    for (int ks = 0; ks < 8; ++ks)
        pb[ks] = *(const half8_t*)&PL[lpix * 256 + (((ks * 4 + kg) ^ psw) << 3)];

    float* ya = y + (size_t)a * ND * HW + pixbase + lpix;
    const half8_t* W2v = (const half8_t*)W2p;
#pragma unroll
    for (int dtg = 0; dtg < 4; ++dtg) {
        floatx4 acc[4] = {{0.f,0.f,0.f,0.f},{0.f,0.f,0.f,0.f},
                          {0.f,0.f,0.f,0.f},{0.f,0.f,0.f,0.f}};
#pragma unroll
        for (int ks = 0; ks < 8; ++ks) {
#pragma unroll
            for (int i = 0; i < 4; ++i) {
                int dt = dtg * 4 + i;
                acc[i] = __builtin_amdgcn_mfma_f32_16x16x32_f16(
                             W2v[(dt * 8 + ks) * 64 + l], pb[ks], acc[i], 0, 0, 0);
            }
        }
#pragma unroll
        for (int i = 0; i < 4; ++i) {
            int d0 = (dtg * 4 + i) * 16 + kg * 4;
#pragma unroll
            for (int r2 = 0; r2 < 4; ++r2)
                ya[(size_t)(d0 + r2) * HW] = acc[i][r2] * INV_MSCALE2;
        }
    }
}

// ---------------------------------------------------------------------------
// stats: one block per (a,d); mean + biased var over the contiguous 4096 row
// ---------------------------------------------------------------------------
__global__ __launch_bounds__(256) void stats_kernel(
        const float* __restrict__ y, float* __restrict__ mean_o,
        float* __restrict__ istd_o) {
    const int ad = blockIdx.x;
    const float* row = y + (size_t)ad * HW;
    const int t = threadIdx.x;
    float s = 0.f, ss = 0.f;
#pragma unroll
    for (int q = 0; q < 4; ++q) {
        float4 v = *(const float4*)&row[4 * (t + q * 256)];
        s  += v.x + v.y + v.z + v.w;
        ss += v.x * v.x + v.y * v.y + v.z * v.z + v.w * v.w;
    }
#pragma unroll
    for (int off = 32; off > 0; off >>= 1) {
        s  += __shfl_down(s, off);
        ss += __shfl_down(ss, off);
    }
    __shared__ float ps[4], pq[4];
    if ((t & 63) == 0) { ps[t >> 6] = s; pq[t >> 6] = ss; }
    __syncthreads();
    if (t == 0) {
        s  = ps[0] + ps[1] + ps[2] + ps[3];
        ss = pq[0] + pq[1] + pq[2] + pq[3];
        float mean = s * (1.f / HW);
        float var  = ss * (1.f / HW) - mean * mean;
        mean_o[ad] = mean;
        istd_o[ad] = rsqrtf(var + 1e-5f);
    }
}

// ---------------------------------------------------------------------------
// finalize: in-place (y - mean) * istd -> softsign
// ---------------------------------------------------------------------------
__global__ __launch_bounds__(256) void finalize_kernel(
        float* __restrict__ y, const float* __restrict__ mean_a,
        const float* __restrict__ istd_a) {
    const int i4 = blockIdx.x * 256 + threadIdx.x;   // float4 index
    const int ad = i4 >> 10;                          // 1024 float4 per (a,d)
    const float m = mean_a[ad], s = istd_a[ad];
    float4 v = ((const float4*)y)[i4];
    float vv[4] = {v.x, v.y, v.z, v.w};
#pragma unroll
    for (int lq = 0; lq < 4; ++lq) {
        float z = (vv[lq] - m) * s;
        vv[lq] = z / (1.f + fabsf(z));
    }
    ((float4*)y)[i4] = make_float4(vv[0], vv[1], vv[2], vv[3]);
}

// ---------------------------------------------------------------------------
extern "C" void kernel_launch(void* const* d_in, const int* in_sizes, int n_in,
                              void* d_out, int out_size, void* d_ws, size_t ws_size,
                              hipStream_t stream) {
    const float* x      = (const float*)d_in[0];
    const float* w_core = (const float*)d_in[1];
    const float* w_out  = (const float*)d_in[2];
    float* y = (float*)d_out;                 // y computed in-place in d_out

    _Float16* W1p = (_Float16*)d_ws;          // 65536 f16 = 128KB
    _Float16* W2p = W1p + 65536;              // 128KB
    float* mean_a = (float*)(W2p + 65536);    // 4096 f32
    float* istd_a = mean_a + 4096;            // 4096 f32   (total 288KB)

    prep_weights<<<64, 256, 0, stream>>>(w_core, w_out, W1p, W2p);
    compute_y<<<1024, 256, 0, stream>>>(x, W1p, W2p, y);
    stats_kernel<<<4096, 256, 0, stream>>>(y, mean_a, istd_a);
    finalize_kernel<<<16384, 256, 0, stream>>>(y, mean_a, istd_a);
}